// Round 12
// baseline (165.682 us; speedup 1.0000x reference)
//
#include <hip/hip_runtime.h>

#define L 21
#define C0 32
#define C1 32
#define IN_DIM 7
#define GHIST 256
#define BPAD 256  // bucket padding -> every 256-slot chunk is layer-uniform

// ---------------- K1: per-block histogram of idx ----------------
__global__ __launch_bounds__(256) void k_hist(const int* __restrict__ idx, int E,
                                              int* __restrict__ blockCounts) {
  __shared__ int h[L];
  int tid = threadIdx.x;
  if (tid < L) h[tid] = 0;
  __syncthreads();
  int per = (E + GHIST - 1) / GHIST;
  int s = blockIdx.x * per;
  int e = min(E, s + per);
  for (int i = s + tid; i < e; i += blockDim.x)
    atomicAdd(&h[idx[i]], 1);
  __syncthreads();
  if (tid < L) blockCounts[blockIdx.x * L + tid] = h[tid];
}

// ---------------- K2: totals, 256-padded bases, per-block cursors -------------
__global__ __launch_bounds__(256) void k_scan(const int* __restrict__ blockCounts,
                                              int* __restrict__ cursor,
                                              int* __restrict__ endArr,
                                              int* __restrict__ baseArr) {
  __shared__ int tot[L];
  __shared__ int base[L + 1];
  int tid = threadIdx.x;
  if (tid < L) {
    int s = 0;
#pragma unroll 8
    for (int b = 0; b < GHIST; b++) s += blockCounts[b * L + tid];
    tot[tid] = s;
  }
  __syncthreads();
  if (tid == 0) {
    int a = 0;
    for (int l = 0; l < L; l++) { base[l] = a; a += (tot[l] + BPAD - 1) & ~(BPAD - 1); }
    base[L] = a;
  }
  __syncthreads();
  if (tid < L) {
    int a = base[tid];
#pragma unroll 8
    for (int b = 0; b < GHIST; b++) {
      cursor[b * L + tid] = a;
      a += blockCounts[b * L + tid];
    }
    endArr[tid] = base[tid] + tot[tid];
  }
  if (tid <= L) baseArr[tid] = base[tid];
}

// ---------------- K3: scatter edge ids + rank + gather input rows -------------
__global__ __launch_bounds__(256) void k_scatter(const int* __restrict__ idx,
                                                 const float* __restrict__ inp, int E,
                                                 const int* __restrict__ cursor,
                                                 int* __restrict__ perm,
                                                 int* __restrict__ rank,
                                                 float* __restrict__ xb) {
  __shared__ int cur[L];
  int tid = threadIdx.x;
  if (tid < L) cur[tid] = cursor[blockIdx.x * L + tid];
  __syncthreads();
  int per = (E + GHIST - 1) / GHIST;
  int s = blockIdx.x * per;
  int e = min(E, s + per);
  for (int i = s + tid; i < e; i += blockDim.x) {
    int l = idx[i];
    int pos = atomicAdd(&cur[l], 1);
    perm[pos] = i;
    rank[i] = pos;
    const float* row = inp + (size_t)i * IN_DIM;
    float4 a, b;
    a.x = row[0]; a.y = row[1]; a.z = row[2]; a.w = row[3];
    b.x = row[4]; b.y = row[5]; b.z = row[6]; b.w = 0.f;
    float4* dst = (float4*)(xb + (size_t)pos * 8);
    dst[0] = a;
    dst[1] = b;
  }
}

// ---------------- K4: compute (R6 body). MODE:
//  1 = xb loads, perm-scattered out stores (R6 exact, fallback)
//  2 = xb loads, SEQUENTIAL stores to scratch in slot order (streaming)
template <int MODE>
__global__ __launch_bounds__(256) void k_compute(const float* __restrict__ xb,
                                                 const float* __restrict__ W0g,
                                                 const float* __restrict__ b0g,
                                                 const float* __restrict__ W1g,
                                                 const float* __restrict__ b1g,
                                                 const int* __restrict__ perm,
                                                 const int* __restrict__ baseArr,
                                                 const int* __restrict__ endArr,
                                                 float* __restrict__ dstbuf) {
  int T = threadIdx.x;
  int lane = T & 63;
  int blockbase = blockIdx.x << 8;

  // derive this block's layer from baseArr (blocks never straddle buckets)
  int bv = baseArr[lane <= L ? lane : L];
  unsigned long long m = __ballot((lane <= L) && (blockbase >= bv));
  int l = __popcll(m) - 1;
  if (l >= L) return;  // uniform across block
  l = __builtin_amdgcn_readfirstlane(l);
  int end = __builtin_amdgcn_readfirstlane(endArr[l]);

  int slot = blockbase + T;

  const float4* xrow = (const float4*)(xb + (size_t)slot * 8);
  float4 xa = xrow[0], xc = xrow[1];
  float x[IN_DIM] = {xa.x, xa.y, xa.z, xa.w, xc.x, xc.y, xc.z};

  const float* w0 = W0g + l * (IN_DIM * C0);
  const float* B0 = b0g + l * C0;
  const float* w1 = W1g + l * (C0 * C1);
  const float* B1 = b1g + l * C1;

  float h[C0];
#pragma unroll
  for (int c = 0; c < C0; c++) h[c] = B0[c];
#pragma unroll
  for (int k = 0; k < IN_DIM; k++) {
#pragma unroll
    for (int c = 0; c < C0; c++) h[c] = fmaf(x[k], w0[k * C0 + c], h[c]);
  }
#pragma unroll
  for (int c = 0; c < C0; c++) h[c] = h[c] >= 0.f ? h[c] : 0.2f * h[c];

  float o[C1];
#pragma unroll
  for (int c = 0; c < C1; c++) o[c] = B1[c];
#pragma unroll
  for (int k = 0; k < C0; k++) {
#pragma unroll
    for (int c = 0; c < C1; c++) o[c] = fmaf(h[k], w1[k * C1 + c], o[c]);
  }
#pragma unroll
  for (int c = 0; c < C1; c++) o[c] = o[c] >= 0.f ? o[c] : 0.2f * o[c];

  // ---- per-wave transpose tile (no cross-wave sharing -> no barriers) ----
  __shared__ float obuf[4 * 64 * 32];
  float* tile = &obuf[(T >> 6) * (64 * 32)];
#pragma unroll
  for (int cq = 0; cq < 32; cq += 4) {
    int ad = lane * 32 + (cq ^ ((lane & 7) << 2));
    float4 v = {o[cq], o[cq + 1], o[cq + 2], o[cq + 3]};
    *(float4*)&tile[ad] = v;
  }
  int wavebase = blockbase + (T >> 6) * 64;
  int q = (lane & 7) * 4;
  int rbase = lane >> 3;
#pragma unroll
  for (int step = 0; step < 8; step++) {
    int row = step * 8 + rbase;
    int slot_r = wavebase + row;
    int sw = (row & 7) << 2;
    float4 v = *(const float4*)&tile[row * 32 + (q ^ sw)];
    if (MODE == 2) {
      // sequential by slot: 8 consecutive 128B rows per instr = 1KB streaming
      *(float4*)(dstbuf + (size_t)slot_r * C1 + q) = v;
    } else if (slot_r < end) {
      int p = perm[slot_r];  // scattered 128B rows (R6 fallback)
      *(float4*)(dstbuf + (size_t)p * C1 + q) = v;
    }
  }
}

// ---------------- K5: out[e] = scratch[rank[e]] -- scattered 128B READS
// (pipelined, L3-hot), fully sequential writes.
__global__ __launch_bounds__(256) void k_out(const float* __restrict__ scratch,
                                             const int* __restrict__ rank,
                                             float* __restrict__ out, int E) {
  int T = threadIdx.x;
  int base = blockIdx.x << 8;
  int q = (T & 7) * 4;
#pragma unroll
  for (int j = 0; j < 8; j++) {
    int e = base + j * 32 + (T >> 3);
    if (e < E) {
      int r = rank[e];  // 8-lane broadcast, one 128B txn per 32 edges
      float4 v = *(const float4*)(scratch + (size_t)r * C1 + q);
      *(float4*)(out + (size_t)e * C1 + q) = v;
    }
  }
}

extern "C" void kernel_launch(void* const* d_in, const int* in_sizes, int n_in,
                              void* d_out, int out_size, void* d_ws, size_t ws_size,
                              hipStream_t stream) {
  const float* inp = (const float*)d_in[0];
  const int* idx   = (const int*)d_in[1];
  const float* W0  = (const float*)d_in[2];
  const float* b0  = (const float*)d_in[3];
  const float* W1  = (const float*)d_in[4];
  const float* b1  = (const float*)d_in[5];
  float* out = (float*)d_out;
  int E = in_sizes[1];

  int nBlk = (E + 255) / 256 + L;  // upper bound on padded 256-chunks
  size_t slots = (size_t)nBlk * 256;

  int* ws = (int*)d_ws;
  int* blockCounts = ws;                       // GHIST*L
  int* cursor      = blockCounts + GHIST * L;  // GHIST*L
  int* endArr      = cursor + GHIST * L;       // L
  int* baseArr     = endArr + L;               // L+1
  int* perm        = baseArr + (L + 1);        // slots
  int* rank        = perm + slots;             // E
  size_t ints = (size_t)2 * GHIST * L + L + (L + 1) + slots + E;
  ints = (ints + 3) & ~(size_t)3;              // 16B-align
  float* xb = (float*)(ws + ints);             // slots * 8 floats
  float* scratch = xb + slots * 8;             // slots * 32 floats
  size_t need1 = ints * 4 + slots * 8 * 4;
  size_t need2 = need1 + slots * 32 * 4;
  int mode = ws_size >= need2 ? 2 : (ws_size >= need1 ? 1 : 1);

  k_hist<<<GHIST, 256, 0, stream>>>(idx, E, blockCounts);
  k_scan<<<1, 256, 0, stream>>>(blockCounts, cursor, endArr, baseArr);
  k_scatter<<<GHIST, 256, 0, stream>>>(idx, inp, E, cursor, perm, rank, xb);

  if (mode == 2) {
    k_compute<2><<<nBlk, 256, 0, stream>>>(xb, W0, b0, W1, b1,
                                           perm, baseArr, endArr, scratch);
    k_out<<<(E + 255) / 256, 256, 0, stream>>>(scratch, rank, out, E);
  } else {
    k_compute<1><<<nBlk, 256, 0, stream>>>(xb, W0, b0, W1, b1,
                                           perm, baseArr, endArr, out);
  }
}

// Round 13
// 101.031 us; speedup vs baseline: 1.6399x; 1.6399x over previous
//
#include <hip/hip_runtime.h>

#define L 21
#define C0 32
#define C1 32
#define IN_DIM 7
#define LSTRIDE 1316  // 1312 + 4-float pad: layer base advances 4 banks/layer
                      // (stride%32==4 -> 8 bank-groups, <=3 layers/group conflict;
                      //  unpadded 1312%32==0 would be a 21-way single-group pileup)
#define SMEM_BYTES (L * LSTRIDE * 4)  // 110,544 B <= 160 KiB/CU

// One fused kernel: all 21 layers' params staged in LDS, one edge per thread,
// original edge order -> sequential input reads AND sequential output writes.
// Divergent per-lane weight reads hit LDS with same-address broadcast merging
// (~20 distinct 16B addrs/wave = ~320B/instr, conflict-bounded by the pad).
__global__ __launch_bounds__(1024) void k_fused(const float* __restrict__ inp,
                                                const int* __restrict__ idx,
                                                const float* __restrict__ W0g,
                                                const float* __restrict__ b0g,
                                                const float* __restrict__ W1g,
                                                const float* __restrict__ b1g,
                                                float* __restrict__ out, int E) {
  extern __shared__ float wbuf[];
  int T = threadIdx.x;
  int e = blockIdx.x * 1024 + T;
  int ec = e < E ? e : 0;

  // ---- issue own-edge loads early (overlap with staging) ----
  int le = idx[ec];
  const float* row = inp + (size_t)ec * IN_DIM;
  float x[IN_DIM];
#pragma unroll
  for (int k = 0; k < IN_DIM; k++) x[k] = row[k];

  // ---- stage all layers' params into bank-padded LDS (coalesced reads) ----
  // per-layer layout: [0,224) W0 [k][c] | [224,256) b0 | [256,1280) W1 [k][c] | [1280,1312) b1
  for (int i = T; i < L * IN_DIM * C0; i += 1024) {
    int l = i / (IN_DIM * C0), r = i - l * (IN_DIM * C0);
    wbuf[l * LSTRIDE + r] = W0g[i];
  }
  for (int i = T; i < L * C0; i += 1024) {
    int l = i >> 5, r = i & 31;
    wbuf[l * LSTRIDE + 224 + r] = b0g[i];
  }
  for (int i = T; i < L * C0 * C1; i += 1024) {
    int l = i >> 10, r = i & 1023;
    wbuf[l * LSTRIDE + 256 + r] = W1g[i];
  }
  for (int i = T; i < L * C1; i += 1024) {
    int l = i >> 5, r = i & 31;
    wbuf[l * LSTRIDE + 1280 + r] = b1g[i];
  }
  __syncthreads();

  const float* wl = &wbuf[le * LSTRIDE];  // per-lane layer base (16B-aligned: 1316*4%16==0)

  // ---- layer 0: h = leaky(x . W0 + b0) ----
  float h[C0];
  {
    const float4* bv = (const float4*)&wl[IN_DIM * C0];
#pragma unroll
    for (int c4 = 0; c4 < 8; c4++) {
      float4 b = bv[c4];
      h[c4 * 4 + 0] = b.x; h[c4 * 4 + 1] = b.y;
      h[c4 * 4 + 2] = b.z; h[c4 * 4 + 3] = b.w;
    }
  }
#pragma unroll
  for (int k = 0; k < IN_DIM; k++) {
    const float4* wk = (const float4*)&wl[k * C0];
#pragma unroll
    for (int c4 = 0; c4 < 8; c4++) {
      float4 w = wk[c4];
      h[c4 * 4 + 0] = fmaf(x[k], w.x, h[c4 * 4 + 0]);
      h[c4 * 4 + 1] = fmaf(x[k], w.y, h[c4 * 4 + 1]);
      h[c4 * 4 + 2] = fmaf(x[k], w.z, h[c4 * 4 + 2]);
      h[c4 * 4 + 3] = fmaf(x[k], w.w, h[c4 * 4 + 3]);
    }
  }
#pragma unroll
  for (int c = 0; c < C0; c++) h[c] = h[c] >= 0.f ? h[c] : 0.2f * h[c];

  // ---- layer 1: o = leaky(h . W1 + b1) ----
  float o[C1];
  {
    const float4* bv = (const float4*)&wl[1280];
#pragma unroll
    for (int c4 = 0; c4 < 8; c4++) {
      float4 b = bv[c4];
      o[c4 * 4 + 0] = b.x; o[c4 * 4 + 1] = b.y;
      o[c4 * 4 + 2] = b.z; o[c4 * 4 + 3] = b.w;
    }
  }
#pragma unroll
  for (int k = 0; k < C0; k++) {
    const float4* wk = (const float4*)&wl[256 + k * C1];
#pragma unroll
    for (int c4 = 0; c4 < 8; c4++) {
      float4 w = wk[c4];
      o[c4 * 4 + 0] = fmaf(h[k], w.x, o[c4 * 4 + 0]);
      o[c4 * 4 + 1] = fmaf(h[k], w.y, o[c4 * 4 + 1]);
      o[c4 * 4 + 2] = fmaf(h[k], w.z, o[c4 * 4 + 2]);
      o[c4 * 4 + 3] = fmaf(h[k], w.w, o[c4 * 4 + 3]);
    }
  }
#pragma unroll
  for (int c = 0; c < C1; c++) o[c] = o[c] >= 0.f ? o[c] : 0.2f * o[c];

  // ---- sequential-by-edge output row (lines fully covered by this wave) ----
  if (e < E) {
    float* orow = out + (size_t)e * C1;
#pragma unroll
    for (int j = 0; j < 8; j++) {
      float4 v = {o[j * 4], o[j * 4 + 1], o[j * 4 + 2], o[j * 4 + 3]};
      *(float4*)(orow + j * 4) = v;
    }
  }
}

extern "C" void kernel_launch(void* const* d_in, const int* in_sizes, int n_in,
                              void* d_out, int out_size, void* d_ws, size_t ws_size,
                              hipStream_t stream) {
  const float* inp = (const float*)d_in[0];
  const int* idx   = (const int*)d_in[1];
  const float* W0  = (const float*)d_in[2];
  const float* b0  = (const float*)d_in[3];
  const float* W1  = (const float*)d_in[4];
  const float* b1  = (const float*)d_in[5];
  float* out = (float*)d_out;
  int E = in_sizes[1];

  // allow >64KB dynamic LDS (gfx950 HW: 160 KiB/WG; idempotent, capture-safe)
  (void)hipFuncSetAttribute((const void*)k_fused,
                            hipFuncAttributeMaxDynamicSharedMemorySize,
                            SMEM_BYTES);

  int nBlk = (E + 1023) / 1024;
  k_fused<<<nBlk, 1024, SMEM_BYTES, stream>>>(inp, idx, W0, b0, W1, b1, out, E);
}